// Round 6
// baseline (417.578 us; speedup 1.0000x reference)
//
#include <hip/hip_runtime.h>

typedef __attribute__((ext_vector_type(8))) __bf16 bf16x8;
typedef __attribute__((ext_vector_type(8))) unsigned short u16x8;
typedef __attribute__((ext_vector_type(4))) float f32x4;

// Static device scratch (bf16):
//  xbf [2048][2048], WtQKV [3072][2048], WtO [2048][2048],
//  q [2048][2048], k [2048][512], v [2048][512], att [2048][2048]
#define XBOFF 0
#define WQKVOFF (XBOFF + 2048 * 2048)
#define WOOFF   (WQKVOFF + 3072 * 2048)
#define QOFF    (WOOFF + 2048 * 2048)
#define KOFF    (QOFF + 2048 * 2048)
#define VOFF    (KOFF + 2048 * 512)
#define AOFF    (VOFF + 2048 * 512)
__device__ ushort g_scratch[AOFF + 2048 * 2048];

// Split-K attention partials (fp32). slot = ((b*16+h)*16+qt)*4 + chunk.
// g_po[slot][64 rows][128 cols]; g_pm/g_pl[slot][3 levels][64 rows].
__device__ float g_po[2048 * 8192];
__device__ float g_pm[2048 * 192];
__device__ float g_pl[2048 * 192];

// nested (matryoshka) index -> full-layout index, H heads/groups, 128/head
__device__ __forceinline__ int nest_map(int n, int H) {
    int h = n >> 7, j = n & 127;
    if (j < 32) return h * 32 + j;
    if (j < 64) return H * 32 + h * 32 + (j - 32);
    return H * 64 + h * 64 + (j - 64);
}

__device__ __forceinline__ ushort f2bf(float f) {
    unsigned u = __builtin_bit_cast(unsigned, f);
    u += 0x7fffu + ((u >> 16) & 1u);
    return (ushort)(u >> 16);
}
__device__ __forceinline__ bf16x8 ld_frag(const ushort* p) {
    return __builtin_bit_cast(bf16x8, *(const u16x8*)p);
}
// async 16B global->LDS (m97 pattern); s must be wave-uniform
__device__ __forceinline__ void glds16(const ushort* g, ushort* s) {
    __builtin_amdgcn_global_load_lds(
        (const __attribute__((address_space(1))) void*)g,
        (__attribute__((address_space(3))) void*)s, 16, 0, 0);
}

// ---------------------------------------------------------------------------
// x fp32 -> bf16. 2048 blocks x 256 thr x 8 elems.
// ---------------------------------------------------------------------------
__global__ __launch_bounds__(256) void cvt_x_kernel(const float* __restrict__ x)
{
    size_t i = ((size_t)blockIdx.x * 256 + threadIdx.x) * 8;
    float4 f0 = *(const float4*)&x[i];
    float4 f1 = *(const float4*)&x[i + 4];
    union { uint4 v; ushort u[8]; } a;
    a.u[0] = f2bf(f0.x); a.u[1] = f2bf(f0.y); a.u[2] = f2bf(f0.z); a.u[3] = f2bf(f0.w);
    a.u[4] = f2bf(f1.x); a.u[5] = f2bf(f1.y); a.u[6] = f2bf(f1.z); a.u[7] = f2bf(f1.w);
    *(uint4*)&g_scratch[XBOFF + i] = a.v;
}

// ---------------------------------------------------------------------------
// Weight transpose+convert, nest reorder folded in.
// mode 0: Wt[n][k] = W[k][nest_map(n,H)]  (QKV)   mode 1: Wt[n][k] = W[nest_map(k,16)][n] (O)
// ---------------------------------------------------------------------------
__global__ __launch_bounds__(256) void transpose_w_kernel(
    const float* __restrict__ W, int rowlen, int H, int mode, int dstoff)
{
    __shared__ ushort T[64][66];
    const int k0 = blockIdx.x * 64;
    const int n0 = blockIdx.y * 64;
    const int t = threadIdx.x;
    const int r = t >> 3, oct = t & 7;

    #pragma unroll
    for (int rep = 0; rep < 2; ++rep) {
        int rr = r + rep * 32;
        int wrow = mode ? nest_map(k0 + rr, 16) : (k0 + rr);
        int wcol = mode ? (n0 + oct * 8) : nest_map(n0 + oct * 8, H);
        float4 f0 = *(const float4*)&W[(size_t)wrow * rowlen + wcol];
        float4 f1 = *(const float4*)&W[(size_t)wrow * rowlen + wcol + 4];
        ushort* d = &T[rr][oct * 8];
        d[0] = f2bf(f0.x); d[1] = f2bf(f0.y); d[2] = f2bf(f0.z); d[3] = f2bf(f0.w);
        d[4] = f2bf(f1.x); d[5] = f2bf(f1.y); d[6] = f2bf(f1.z); d[7] = f2bf(f1.w);
    }
    __syncthreads();
    #pragma unroll
    for (int rep = 0; rep < 2; ++rep) {
        int rr = r + rep * 32;
        union { uint4 v; ushort u[8]; } cv;
        #pragma unroll
        for (int i = 0; i < 8; ++i) cv.u[i] = T[oct * 8 + i][rr];
        *(uint4*)&g_scratch[dstoff + (size_t)(n0 + rr) * 2048 + k0 + oct * 8] = cv.v;
    }
}

// ---------------------------------------------------------------------------
// 128x128-tile GEMM, BK=64, global_load_lds(16B) staging into XOR-swizzled
// unpadded LDS (physical chunk = logical_chunk ^ (row&7); 2-way banks = free).
// mode 0: A=xbf, Bt=WtQKV (N=3072) -> q|k|v bf16.  mode 1: A=att, Bt=WtO -> fp32 out.
// ---------------------------------------------------------------------------
__global__ __launch_bounds__(256) void gemm128_kernel(
    const float* __restrict__ b0, const float* __restrict__ b1,
    const float* __restrict__ b2, float* __restrict__ oext, int mode)
{
    __shared__ __align__(16) ushort As[128 * 64];
    __shared__ __align__(16) ushort Bs[128 * 64];
    const int n0 = blockIdx.x * 128;
    const int m0 = blockIdx.y * 128;
    const int tid = threadIdx.x;
    const int lane = tid & 63, wid = tid >> 6;
    const int wm = wid & 1, wn = wid >> 1;
    const int quad = lane >> 4, l16 = lane & 15;

    const ushort* A  = g_scratch + (mode ? AOFF : XBOFF);
    const ushort* Bt = g_scratch + (mode ? WOOFF : WQKVOFF);

    // epilogue routing (block-uniform)
    const float* bias; ushort* outS = nullptr; int c0, oldim, H;
    if (mode == 1)      { bias = b0; c0 = n0; oldim = 2048; H = 0; }
    else if (n0 < 2048) { bias = b0; outS = g_scratch + QOFF; c0 = n0;        oldim = 2048; H = 16; }
    else if (n0 < 2560) { bias = b1; outS = g_scratch + KOFF; c0 = n0 - 2048; oldim = 512;  H = 4; }
    else                { bias = b2; outS = g_scratch + VOFF; c0 = n0 - 2560; oldim = 512;  H = 4; }

    // staging: lane i of each wave loads logical chunk c = (i&7)^((i>>3)&7)
    // of row rbase + (i>>3); HW lands it at LDS slot i (= swizzled layout)
    const int lrow = lane >> 3;
    const int lchunk = (lane & 7) ^ (lrow & 7);

    f32x4 acc[4][4];
    #pragma unroll
    for (int a = 0; a < 4; ++a)
        #pragma unroll
        for (int c = 0; c < 4; ++c) acc[a][c] = f32x4{0.f, 0.f, 0.f, 0.f};

    for (int kt = 0; kt < 32; ++kt) {
        const int k0 = kt * 64;
        #pragma unroll
        for (int it = 0; it < 4; ++it) {
            int rb = it * 32 + wid * 8;            // wave-uniform row base
            int r  = rb + lrow;
            glds16(&A[(size_t)(m0 + r) * 2048 + k0 + lchunk * 8], &As[rb * 64]);
            glds16(&Bt[(size_t)(n0 + r) * 2048 + k0 + lchunk * 8], &Bs[rb * 64]);
        }
        __syncthreads();   // drains vmcnt (glds) per barrier semantics
        #pragma unroll
        for (int kc = 0; kc < 2; ++kc) {
            bf16x8 af[4], bf[4];
            #pragma unroll
            for (int s = 0; s < 4; ++s) {
                int ra = wm * 64 + s * 16 + l16;
                int rbv = wn * 64 + s * 16 + l16;
                int ch = kc * 4 + quad;
                af[s] = ld_frag(&As[ra * 64 + ((ch ^ (ra & 7)) * 8)]);
                bf[s] = ld_frag(&Bs[rbv * 64 + ((ch ^ (rbv & 7)) * 8)]);
            }
            #pragma unroll
            for (int sm = 0; sm < 4; ++sm)
                #pragma unroll
                for (int sn = 0; sn < 4; ++sn)
                    acc[sm][sn] = __builtin_amdgcn_mfma_f32_16x16x32_bf16(
                        af[sm], bf[sn], acc[sm][sn], 0, 0, 0);
        }
        __syncthreads();
    }

    #pragma unroll
    for (int sm = 0; sm < 4; ++sm)
    #pragma unroll
    for (int sn = 0; sn < 4; ++sn)
    #pragma unroll
    for (int i = 0; i < 4; ++i) {
        int row = m0 + wm * 64 + sm * 16 + quad * 4 + i;
        int loc = wn * 64 + sn * 16 + l16;
        float v = acc[sm][sn][i];
        if (mode == 1) {
            oext[(size_t)row * 2048 + c0 + loc] = v + bias[c0 + loc];
        } else {
            v += bias[nest_map(c0 + loc, H)];
            outS[(size_t)row * oldim + c0 + loc] = f2bf(v);
        }
    }
}

// ---------------------------------------------------------------------------
// Split-K matryoshka flash attention. Grid (64, 16, 2): qt = bx&15,
// chunk = bx>>4 covering k-tiles [chunk*4, min(chunk*4+3, qt)]; blocks with
// chunk*4 > qt exit. Writes unnormalized per-chunk partials (o, m, l).
// ---------------------------------------------------------------------------
__global__ __launch_bounds__(256) void attn_split_kernel()
{
    const int bx = blockIdx.x;
    const int qt = bx & 15, chunk = bx >> 4;
    if (chunk * 4 > qt) return;
    const int kts = chunk * 4;
    const int kte = min(kts + 3, qt);

    const ushort* qb = g_scratch + QOFF;   // [B,S,16,128] nested
    const ushort* kb = g_scratch + KOFF;   // [B,S,4,128]
    const ushort* vb = g_scratch + VOFF;   // [B,S,4,128]

    __shared__ ushort Ks[64][136];
    __shared__ ushort Vt[128][72];   // V transposed, XOR-octet swizzled
    __shared__ ushort Ps[64][72];    // P round-trip (wave-private rows)

    const int h = blockIdx.y, b = blockIdx.z;
    const int g = h >> 2;
    const int q0 = qt * 64;
    const int tid = threadIdx.x;
    const int lane = tid & 63, w = tid >> 6;
    const int quad = lane >> 4, l16 = lane & 15;

    // Q fragments in registers (row = q0 + w*16 + l16)
    bf16x8 qa[4];
    {
        const ushort* qrow =
            qb + ((size_t)((b * 1024 + q0 + w * 16 + l16) * 16 + h)) * 128;
        #pragma unroll
        for (int kc = 0; kc < 4; ++kc)
            qa[kc] = ld_frag(qrow + kc * 32 + quad * 8);
    }

    float m_s[3][4], l_s[3][4];
    #pragma unroll
    for (int l = 0; l < 3; ++l)
        #pragma unroll
        for (int i = 0; i < 4; ++i) { m_s[l][i] = -1e9f; l_s[l][i] = 0.0f; }
    f32x4 oacc[8];
    #pragma unroll
    for (int t2 = 0; t2 < 8; ++t2) oacc[t2] = f32x4{0.f, 0.f, 0.f, 0.f};

    f32x4 sdp[4];
    const f32x4 fz = {0.f, 0.f, 0.f, 0.f};

    auto attn_level = [&](int lvl, float scale, int obase, int ontiles, int voff,
                          bool diag, int k0) {
        float sv[4][4], mx[4];
        #pragma unroll
        for (int i = 0; i < 4; ++i) mx[i] = -1e9f;
        #pragma unroll
        for (int n = 0; n < 4; ++n)
            #pragma unroll
            for (int i = 0; i < 4; ++i) {
                float x = sdp[n][i] * scale;
                if (diag) {
                    int kc = k0 + n * 16 + l16;
                    int qr = q0 + w * 16 + quad * 4 + i;
                    if (kc > qr) x = -1e9f;
                }
                sv[n][i] = x;
                mx[i] = fmaxf(mx[i], x);
            }
        #pragma unroll
        for (int d = 1; d < 16; d <<= 1)
            #pragma unroll
            for (int i = 0; i < 4; ++i) mx[i] = fmaxf(mx[i], __shfl_xor(mx[i], d, 64));
        float al[4], rs[4];
        #pragma unroll
        for (int i = 0; i < 4; ++i) {
            float mn = fmaxf(m_s[lvl][i], mx[i]);
            al[i] = __expf(m_s[lvl][i] - mn);
            m_s[lvl][i] = mn;
            rs[i] = 0.f;
        }
        #pragma unroll
        for (int n = 0; n < 4; ++n)
            #pragma unroll
            for (int i = 0; i < 4; ++i) {
                float p = __expf(sv[n][i] - m_s[lvl][i]);
                sv[n][i] = p;
                rs[i] += p;
            }
        #pragma unroll
        for (int d = 1; d < 16; d <<= 1)
            #pragma unroll
            for (int i = 0; i < 4; ++i) rs[i] += __shfl_xor(rs[i], d, 64);
        #pragma unroll
        for (int i = 0; i < 4; ++i) l_s[lvl][i] = l_s[lvl][i] * al[i] + rs[i];
        for (int t = 0; t < ontiles; ++t)
            #pragma unroll
            for (int i = 0; i < 4; ++i) oacc[obase + t][i] *= al[i];
        // P: C-layout regs -> LDS rows [w*16, w*16+16) (wave-private)
        #pragma unroll
        for (int n = 0; n < 4; ++n)
            #pragma unroll
            for (int i = 0; i < 4; ++i)
                Ps[w * 16 + quad * 4 + i][n * 16 + l16] = f2bf(sv[n][i]);
        // PV
        #pragma unroll
        for (int kc = 0; kc < 2; ++kc) {
            bf16x8 pa = ld_frag(&Ps[w * 16 + l16][kc * 32 + quad * 8]);
            for (int t = 0; t < ontiles; ++t) {
                int vd = voff + t * 16 + l16;
                bf16x8 vf = ld_frag(&Vt[vd][(kc * 32 + quad * 8) ^ (((vd >> 3) & 7) << 3)]);
                oacc[obase + t] =
                    __builtin_amdgcn_mfma_f32_16x16x32_bf16(pa, vf, oacc[obase + t], 0, 0, 0);
            }
        }
    };

    for (int kt = kts; kt <= kte; ++kt) {
        const int k0 = kt * 64;
        {   // stage K natural, V transposed+swizzled
            int r = tid >> 4, oct = tid & 15;
            #pragma unroll
            for (int rep = 0; rep < 4; ++rep) {
                int row = r + rep * 16;
                size_t base = (size_t)((b * 1024 + k0 + row) * 4 + g) * 128 + oct * 8;
                *(uint4*)&Ks[row][oct * 8] = *(const uint4*)&kb[base];
                union { uint4 v; ushort u[8]; } cv;
                cv.v = *(const uint4*)&vb[base];
                #pragma unroll
                for (int i = 0; i < 8; ++i) {
                    int d = oct * 8 + i;
                    Vt[d][row ^ (((d >> 3) & 7) << 3)] = cv.u[i];
                }
            }
        }
        __syncthreads();

        const bool diag = (kt == qt);
        #pragma unroll
        for (int n = 0; n < 4; ++n)
            sdp[n] = __builtin_amdgcn_mfma_f32_16x16x32_bf16(
                qa[0], ld_frag(&Ks[n * 16 + l16][quad * 8]), fz, 0, 0, 0);
        attn_level(0, 0.1767766953f, 0, 2, 0, diag, k0);
        #pragma unroll
        for (int n = 0; n < 4; ++n)
            sdp[n] = __builtin_amdgcn_mfma_f32_16x16x32_bf16(
                qa[1], ld_frag(&Ks[n * 16 + l16][32 + quad * 8]), sdp[n], 0, 0, 0);
        attn_level(1, 0.125f, 2, 2, 32, diag, k0);
        #pragma unroll
        for (int kc = 2; kc < 4; ++kc)
            #pragma unroll
            for (int n = 0; n < 4; ++n)
                sdp[n] = __builtin_amdgcn_mfma_f32_16x16x32_bf16(
                    qa[kc], ld_frag(&Ks[n * 16 + l16][kc * 32 + quad * 8]), sdp[n], 0, 0, 0);
        attn_level(2, 0.0883883476f, 4, 4, 64, diag, k0);

        __syncthreads();   // WAR before next staging
    }

    // write partials (unnormalized o + per-level m, l)
    const int slot = ((b * 16 + h) * 16 + qt) * 4 + chunk;
    #pragma unroll
    for (int t = 0; t < 8; ++t)
        #pragma unroll
        for (int i = 0; i < 4; ++i) {
            int row = w * 16 + quad * 4 + i;
            g_po[(size_t)slot * 8192 + row * 128 + t * 16 + l16] = oacc[t][i];
        }
    if (l16 == 0) {
        #pragma unroll
        for (int l = 0; l < 3; ++l)
            #pragma unroll
            for (int i = 0; i < 4; ++i) {
                int row = w * 16 + quad * 4 + i;
                g_pm[slot * 192 + l * 64 + row] = m_s[l][i];
                g_pl[slot * 192 + l * 64 + row] = l_s[l][i];
            }
    }
}

// ---------------------------------------------------------------------------
// Combine <=4 chunk partials per (qt,h,b); normalize; write bf16 att.
// 256 thr: r = tid>>2 (row), part = tid&3 -> level {0,1,2,2}, cols part*32..+31.
// ---------------------------------------------------------------------------
__global__ __launch_bounds__(256) void attn_combine_kernel()
{
    ushort* att = g_scratch + AOFF;
    const int qt = blockIdx.x, h = blockIdx.y, b = blockIdx.z;
    const int nc = (qt >> 2) + 1;
    const int tid = threadIdx.x;
    const int r = tid >> 2, part = tid & 3;
    const int lvl = (part == 0) ? 0 : (part == 1) ? 1 : 2;
    const int d0 = part * 32;
    const int sb = ((b * 16 + h) * 16 + qt) * 4;

    float mc[4], lc[4], wc[4];
    float M = -3e38f;
    for (int c = 0; c < nc; ++c) {
        mc[c] = g_pm[(sb + c) * 192 + lvl * 64 + r];
        lc[c] = g_pl[(sb + c) * 192 + lvl * 64 + r];
        M = fmaxf(M, mc[c]);
    }
    float L = 0.f;
    for (int c = 0; c < nc; ++c) { wc[c] = __expf(mc[c] - M); L += lc[c] * wc[c]; }
    float inv = (L > 0.f) ? (1.f / L) : 0.f;
    for (int c = 0; c < nc; ++c) wc[c] *= inv;

    const int srow = qt * 64 + r;
    const size_t obase = (size_t)((b * 1024 + srow) * 16 + h) * 128 + d0;
    #pragma unroll
    for (int j = 0; j < 8; ++j) {
        float4 s = {0.f, 0.f, 0.f, 0.f};
        for (int c = 0; c < nc; ++c) {
            float4 v = *(const float4*)&g_po[(size_t)(sb + c) * 8192 + r * 128 + d0 + j * 4];
            s.x += v.x * wc[c]; s.y += v.y * wc[c];
            s.z += v.z * wc[c]; s.w += v.w * wc[c];
        }
        ushort4 o4 = { f2bf(s.x), f2bf(s.y), f2bf(s.z), f2bf(s.w) };
        *(ushort4*)&att[obase + j * 4] = o4;
    }
}

// ---------------------------------------------------------------------------
extern "C" void kernel_launch(void* const* d_in, const int* in_sizes, int n_in,
                              void* d_out, int out_size, void* d_ws, size_t ws_size,
                              hipStream_t stream)
{
    const float* x  = (const float*)d_in[0];
    // d_in[1] = mask (bool tril): applied analytically — unused
    const float* Wq = (const float*)d_in[2];
    const float* bq = (const float*)d_in[3];
    const float* Wk = (const float*)d_in[4];
    const float* bk = (const float*)d_in[5];
    const float* Wv = (const float*)d_in[6];
    const float* bv = (const float*)d_in[7];
    const float* Wo = (const float*)d_in[8];
    const float* bo = (const float*)d_in[9];
    float* out = (float*)d_out;
    (void)d_ws; (void)ws_size;

    dim3 blk(256, 1, 1);
    hipLaunchKernelGGL(cvt_x_kernel, dim3(2048), blk, 0, stream, x);
    hipLaunchKernelGGL(transpose_w_kernel, dim3(32, 32), blk, 0, stream,
                       Wq, 2048, 16, 0, WQKVOFF);
    hipLaunchKernelGGL(transpose_w_kernel, dim3(32, 8), blk, 0, stream,
                       Wk, 512, 4, 0, WQKVOFF + 2048 * 2048);
    hipLaunchKernelGGL(transpose_w_kernel, dim3(32, 8), blk, 0, stream,
                       Wv, 512, 4, 0, WQKVOFF + 2560 * 2048);
    hipLaunchKernelGGL(transpose_w_kernel, dim3(32, 32), blk, 0, stream,
                       Wo, 2048, 16, 1, WOOFF);
    hipLaunchKernelGGL(gemm128_kernel, dim3(24, 16), blk, 0, stream,
                       bq, bk, bv, (float*)nullptr, 0);
    hipLaunchKernelGGL(attn_split_kernel, dim3(64, 16, 2), blk, 0, stream);
    hipLaunchKernelGGL(attn_combine_kernel, dim3(16, 16, 2), blk, 0, stream);
    hipLaunchKernelGGL(gemm128_kernel, dim3(16, 16), blk, 0, stream,
                       bo, nullptr, nullptr, out, 1);
}

// Round 7
// 323.149 us; speedup vs baseline: 1.2922x; 1.2922x over previous
//
#include <hip/hip_runtime.h>

typedef __attribute__((ext_vector_type(8))) __bf16 bf16x8;
typedef __attribute__((ext_vector_type(8))) unsigned short u16x8;
typedef __attribute__((ext_vector_type(4))) float f32x4;

// Static device scratch (bf16):
//  xbf [2048][2048], WtQKV [3072][2048], WtO [2048][2048],
//  q [2048][2048], k [2048][512], v [2048][512], att [2048][2048]
#define XBOFF 0
#define WQKVOFF (XBOFF + 2048 * 2048)
#define WOOFF   (WQKVOFF + 3072 * 2048)
#define QOFF    (WOOFF + 2048 * 2048)
#define KOFF    (QOFF + 2048 * 2048)
#define VOFF    (KOFF + 2048 * 512)
#define AOFF    (VOFF + 2048 * 512)
__device__ ushort g_scratch[AOFF + 2048 * 2048];

// nested (matryoshka) index -> full-layout index, H heads/groups, 128/head
__device__ __forceinline__ int nest_map(int n, int H) {
    int h = n >> 7, j = n & 127;
    if (j < 32) return h * 32 + j;
    if (j < 64) return H * 32 + h * 32 + (j - 32);
    return H * 64 + h * 64 + (j - 64);
}

__device__ __forceinline__ ushort f2bf(float f) {
    unsigned u = __builtin_bit_cast(unsigned, f);
    u += 0x7fffu + ((u >> 16) & 1u);
    return (ushort)(u >> 16);
}
__device__ __forceinline__ bf16x8 ld_frag(const ushort* p) {
    return __builtin_bit_cast(bf16x8, *(const u16x8*)p);
}
// async 16B global->LDS (m97 pattern); LDS base must be wave-uniform
__device__ __forceinline__ void glds16(const ushort* g, ushort* s) {
    __builtin_amdgcn_global_load_lds(
        (const __attribute__((address_space(1))) void*)g,
        (__attribute__((address_space(3))) void*)s, 16, 0, 0);
}

// ---------------------------------------------------------------------------
// Fused prep: one dispatch does x cvt + all 4 weight transposes.
// blocks [0,2048): x fp32->bf16 (8 el/thread)
// blocks [2048,3072): Wq^T  [3072,3328): Wk^T  [3328,3584): Wv^T
// blocks [3584,4608): Wo^T (row-mapped)
// ---------------------------------------------------------------------------
__global__ __launch_bounds__(256) void prep_kernel(
    const float* __restrict__ x,
    const float* __restrict__ Wq, const float* __restrict__ Wk,
    const float* __restrict__ Wv, const float* __restrict__ Wo)
{
    const int bx = blockIdx.x;
    const int tid = threadIdx.x;

    if (bx < 2048) {   // ---- x convert ----
        size_t i = ((size_t)bx * 256 + tid) * 8;
        float4 f0 = *(const float4*)&x[i];
        float4 f1 = *(const float4*)&x[i + 4];
        union { uint4 v; ushort u[8]; } a;
        a.u[0] = f2bf(f0.x); a.u[1] = f2bf(f0.y); a.u[2] = f2bf(f0.z); a.u[3] = f2bf(f0.w);
        a.u[4] = f2bf(f1.x); a.u[5] = f2bf(f1.y); a.u[6] = f2bf(f1.z); a.u[7] = f2bf(f1.w);
        *(uint4*)&g_scratch[XBOFF + i] = a.v;
        return;
    }

    // ---- weight transpose tiles ----
    const float* W; int rowlen, H, mode, dstoff, t;
    if (bx < 3072)      { W = Wq; rowlen = 2048; H = 16; mode = 0; dstoff = WQKVOFF;               t = bx - 2048; }
    else if (bx < 3328) { W = Wk; rowlen = 512;  H = 4;  mode = 0; dstoff = WQKVOFF + 2048 * 2048; t = bx - 3072; }
    else if (bx < 3584) { W = Wv; rowlen = 512;  H = 4;  mode = 0; dstoff = WQKVOFF + 2560 * 2048; t = bx - 3328; }
    else                { W = Wo; rowlen = 2048; H = 16; mode = 1; dstoff = WOOFF;                 t = bx - 3584; }
    const int k0 = (t & 31) * 64;
    const int n0 = (t >> 5) * 64;

    __shared__ ushort T[64][66];
    const int r = tid >> 3, oct = tid & 7;

    #pragma unroll
    for (int rep = 0; rep < 2; ++rep) {
        int rr = r + rep * 32;
        int wrow = mode ? nest_map(k0 + rr, 16) : (k0 + rr);
        int wcol = mode ? (n0 + oct * 8) : nest_map(n0 + oct * 8, H);
        float4 f0 = *(const float4*)&W[(size_t)wrow * rowlen + wcol];
        float4 f1 = *(const float4*)&W[(size_t)wrow * rowlen + wcol + 4];
        ushort* d = &T[rr][oct * 8];
        d[0] = f2bf(f0.x); d[1] = f2bf(f0.y); d[2] = f2bf(f0.z); d[3] = f2bf(f0.w);
        d[4] = f2bf(f1.x); d[5] = f2bf(f1.y); d[6] = f2bf(f1.z); d[7] = f2bf(f1.w);
    }
    __syncthreads();
    #pragma unroll
    for (int rep = 0; rep < 2; ++rep) {
        int rr = r + rep * 32;
        union { uint4 v; ushort u[8]; } cv;
        #pragma unroll
        for (int i = 0; i < 8; ++i) cv.u[i] = T[oct * 8 + i][rr];
        *(uint4*)&g_scratch[dstoff + (size_t)(n0 + rr) * 2048 + k0 + oct * 8] = cv.v;
    }
}

// ---------------------------------------------------------------------------
// 128x128-tile GEMM, BK=64, global_load_lds(16B) staging into XOR-swizzled
// unpadded LDS (physical chunk = logical_chunk ^ (row&7)).
// mode 0: A=xbf, Bt=WtQKV (N=3072) -> q|k|v bf16.  mode 1: A=att, Bt=WtO -> fp32 out.
// ---------------------------------------------------------------------------
__global__ __launch_bounds__(256) void gemm128_kernel(
    const float* __restrict__ b0, const float* __restrict__ b1,
    const float* __restrict__ b2, float* __restrict__ oext, int mode)
{
    __shared__ __align__(16) ushort As[128 * 64];
    __shared__ __align__(16) ushort Bs[128 * 64];
    const int n0 = blockIdx.x * 128;
    const int m0 = blockIdx.y * 128;
    const int tid = threadIdx.x;
    const int lane = tid & 63, wid = tid >> 6;
    const int wm = wid & 1, wn = wid >> 1;
    const int quad = lane >> 4, l16 = lane & 15;

    const ushort* A  = g_scratch + (mode ? AOFF : XBOFF);
    const ushort* Bt = g_scratch + (mode ? WOOFF : WQKVOFF);

    // epilogue routing (block-uniform)
    const float* bias; ushort* outS = nullptr; int c0, oldim, H;
    if (mode == 1)      { bias = b0; c0 = n0; oldim = 2048; H = 0; }
    else if (n0 < 2048) { bias = b0; outS = g_scratch + QOFF; c0 = n0;        oldim = 2048; H = 16; }
    else if (n0 < 2560) { bias = b1; outS = g_scratch + KOFF; c0 = n0 - 2048; oldim = 512;  H = 4; }
    else                { bias = b2; outS = g_scratch + VOFF; c0 = n0 - 2560; oldim = 512;  H = 4; }

    const int lrow = lane >> 3;
    const int lchunk = (lane & 7) ^ (lrow & 7);

    f32x4 acc[4][4];
    #pragma unroll
    for (int a = 0; a < 4; ++a)
        #pragma unroll
        for (int c = 0; c < 4; ++c) acc[a][c] = f32x4{0.f, 0.f, 0.f, 0.f};

    for (int kt = 0; kt < 32; ++kt) {
        const int k0 = kt * 64;
        #pragma unroll
        for (int it = 0; it < 4; ++it) {
            int rb = it * 32 + wid * 8;            // wave-uniform row base
            int r  = rb + lrow;
            glds16(&A[(size_t)(m0 + r) * 2048 + k0 + lchunk * 8], &As[rb * 64]);
            glds16(&Bt[(size_t)(n0 + r) * 2048 + k0 + lchunk * 8], &Bs[rb * 64]);
        }
        __syncthreads();
        #pragma unroll
        for (int kc = 0; kc < 2; ++kc) {
            bf16x8 af[4], bf[4];
            #pragma unroll
            for (int s = 0; s < 4; ++s) {
                int ra = wm * 64 + s * 16 + l16;
                int rbv = wn * 64 + s * 16 + l16;
                int ch = kc * 4 + quad;
                af[s] = ld_frag(&As[ra * 64 + ((ch ^ (ra & 7)) * 8)]);
                bf[s] = ld_frag(&Bs[rbv * 64 + ((ch ^ (rbv & 7)) * 8)]);
            }
            #pragma unroll
            for (int sm = 0; sm < 4; ++sm)
                #pragma unroll
                for (int sn = 0; sn < 4; ++sn)
                    acc[sm][sn] = __builtin_amdgcn_mfma_f32_16x16x32_bf16(
                        af[sm], bf[sn], acc[sm][sn], 0, 0, 0);
        }
        __syncthreads();
    }

    #pragma unroll
    for (int sm = 0; sm < 4; ++sm)
    #pragma unroll
    for (int sn = 0; sn < 4; ++sn)
    #pragma unroll
    for (int i = 0; i < 4; ++i) {
        int row = m0 + wm * 64 + sm * 16 + quad * 4 + i;
        int loc = wn * 64 + sn * 16 + l16;
        float v = acc[sm][sn][i];
        if (mode == 1) {
            oext[(size_t)row * 2048 + c0 + loc] = v + bias[c0 + loc];
        } else {
            v += bias[nest_map(c0 + loc, H)];
            outS[(size_t)row * oldim + c0 + loc] = f2bf(v);
        }
    }
}

// ---------------------------------------------------------------------------
// Matryoshka flash attention (round-5 structure). Grid (16,16,2), 4 waves;
// wave w owns q-rows [w*16,w*16+16). qt = 15 - blockIdx.x. Q in registers,
// Ps wave-private (no barriers), 2 barriers per k-tile.
// ---------------------------------------------------------------------------
__global__ __launch_bounds__(256) void attn_kernel()
{
    const ushort* qb = g_scratch + QOFF;   // [B,S,16,128] nested
    const ushort* kb = g_scratch + KOFF;   // [B,S,4,128]
    const ushort* vb = g_scratch + VOFF;   // [B,S,4,128]
    ushort* att = g_scratch + AOFF;        // [B,S,16,128] nested

    __shared__ ushort Ks[64][136];
    __shared__ ushort Vt[128][72];   // V transposed, XOR-octet swizzled
    __shared__ ushort Ps[64][72];    // P round-trip (wave-private rows)

    const int qt = 15 - blockIdx.x, h = blockIdx.y, b = blockIdx.z;
    const int g = h >> 2;
    const int q0 = qt * 64;
    const int tid = threadIdx.x;
    const int lane = tid & 63, w = tid >> 6;
    const int quad = lane >> 4, l16 = lane & 15;

    bf16x8 qa[4];
    {
        const ushort* qrow =
            qb + ((size_t)((b * 1024 + q0 + w * 16 + l16) * 16 + h)) * 128;
        #pragma unroll
        for (int kc = 0; kc < 4; ++kc)
            qa[kc] = ld_frag(qrow + kc * 32 + quad * 8);
    }

    float m_s[3][4], l_s[3][4];
    #pragma unroll
    for (int l = 0; l < 3; ++l)
        #pragma unroll
        for (int i = 0; i < 4; ++i) { m_s[l][i] = -1e9f; l_s[l][i] = 0.0f; }
    f32x4 oacc[8];
    #pragma unroll
    for (int t2 = 0; t2 < 8; ++t2) oacc[t2] = f32x4{0.f, 0.f, 0.f, 0.f};

    f32x4 sdp[4];
    const f32x4 fz = {0.f, 0.f, 0.f, 0.f};

    auto attn_level = [&](int lvl, float scale, int obase, int ontiles, int voff,
                          bool diag, int k0) {
        float sv[4][4], mx[4];
        #pragma unroll
        for (int i = 0; i < 4; ++i) mx[i] = -1e9f;
        #pragma unroll
        for (int n = 0; n < 4; ++n)
            #pragma unroll
            for (int i = 0; i < 4; ++i) {
                float x = sdp[n][i] * scale;
                if (diag) {
                    int kc = k0 + n * 16 + l16;
                    int qr = q0 + w * 16 + quad * 4 + i;
                    if (kc > qr) x = -1e9f;
                }
                sv[n][i] = x;
                mx[i] = fmaxf(mx[i], x);
            }
        #pragma unroll
        for (int d = 1; d < 16; d <<= 1)
            #pragma unroll
            for (int i = 0; i < 4; ++i) mx[i] = fmaxf(mx[i], __shfl_xor(mx[i], d, 64));
        float al[4], rs[4];
        #pragma unroll
        for (int i = 0; i < 4; ++i) {
            float mn = fmaxf(m_s[lvl][i], mx[i]);
            al[i] = __expf(m_s[lvl][i] - mn);
            m_s[lvl][i] = mn;
            rs[i] = 0.f;
        }
        #pragma unroll
        for (int n = 0; n < 4; ++n)
            #pragma unroll
            for (int i = 0; i < 4; ++i) {
                float p = __expf(sv[n][i] - m_s[lvl][i]);
                sv[n][i] = p;
                rs[i] += p;
            }
        #pragma unroll
        for (int d = 1; d < 16; d <<= 1)
            #pragma unroll
            for (int i = 0; i < 4; ++i) rs[i] += __shfl_xor(rs[i], d, 64);
        #pragma unroll
        for (int i = 0; i < 4; ++i) l_s[lvl][i] = l_s[lvl][i] * al[i] + rs[i];
        for (int t = 0; t < ontiles; ++t)
            #pragma unroll
            for (int i = 0; i < 4; ++i) oacc[obase + t][i] *= al[i];
        #pragma unroll
        for (int n = 0; n < 4; ++n)
            #pragma unroll
            for (int i = 0; i < 4; ++i)
                Ps[w * 16 + quad * 4 + i][n * 16 + l16] = f2bf(sv[n][i]);
        #pragma unroll
        for (int kc = 0; kc < 2; ++kc) {
            bf16x8 pa = ld_frag(&Ps[w * 16 + l16][kc * 32 + quad * 8]);
            for (int t = 0; t < ontiles; ++t) {
                int vd = voff + t * 16 + l16;
                bf16x8 vf = ld_frag(&Vt[vd][(kc * 32 + quad * 8) ^ (((vd >> 3) & 7) << 3)]);
                oacc[obase + t] =
                    __builtin_amdgcn_mfma_f32_16x16x32_bf16(pa, vf, oacc[obase + t], 0, 0, 0);
            }
        }
    };

    for (int kt = 0; kt <= qt; ++kt) {
        const int k0 = kt * 64;
        {
            int r = tid >> 4, oct = tid & 15;
            #pragma unroll
            for (int rep = 0; rep < 4; ++rep) {
                int row = r + rep * 16;
                size_t base = (size_t)((b * 1024 + k0 + row) * 4 + g) * 128 + oct * 8;
                *(uint4*)&Ks[row][oct * 8] = *(const uint4*)&kb[base];
                union { uint4 v; ushort u[8]; } cv;
                cv.v = *(const uint4*)&vb[base];
                #pragma unroll
                for (int i = 0; i < 8; ++i) {
                    int d = oct * 8 + i;
                    Vt[d][row ^ (((d >> 3) & 7) << 3)] = cv.u[i];
                }
            }
        }
        __syncthreads();

        const bool diag = (kt == qt);
        #pragma unroll
        for (int n = 0; n < 4; ++n)
            sdp[n] = __builtin_amdgcn_mfma_f32_16x16x32_bf16(
                qa[0], ld_frag(&Ks[n * 16 + l16][quad * 8]), fz, 0, 0, 0);
        attn_level(0, 0.1767766953f, 0, 2, 0, diag, k0);
        #pragma unroll
        for (int n = 0; n < 4; ++n)
            sdp[n] = __builtin_amdgcn_mfma_f32_16x16x32_bf16(
                qa[1], ld_frag(&Ks[n * 16 + l16][32 + quad * 8]), sdp[n], 0, 0, 0);
        attn_level(1, 0.125f, 2, 2, 32, diag, k0);
        #pragma unroll
        for (int kc = 2; kc < 4; ++kc)
            #pragma unroll
            for (int n = 0; n < 4; ++n)
                sdp[n] = __builtin_amdgcn_mfma_f32_16x16x32_bf16(
                    qa[kc], ld_frag(&Ks[n * 16 + l16][kc * 32 + quad * 8]), sdp[n], 0, 0, 0);
        attn_level(2, 0.0883883476f, 4, 4, 64, diag, k0);

        __syncthreads();
    }

    float inv[3][4];
    #pragma unroll
    for (int l = 0; l < 3; ++l)
        #pragma unroll
        for (int i = 0; i < 4; ++i) {
            float L = l_s[l][i];
            inv[l][i] = (L > 0.f) ? (1.0f / L) : 0.f;
        }
    #pragma unroll
    for (int t = 0; t < 8; ++t) {
        int lvl = (t < 2) ? 0 : (t < 4) ? 1 : 2;
        #pragma unroll
        for (int i = 0; i < 4; ++i) {
            int srow = q0 + w * 16 + quad * 4 + i;
            att[(size_t)((b * 1024 + srow) * 16 + h) * 128 + t * 16 + l16] =
                f2bf(oacc[t][i] * inv[lvl][i]);
        }
    }
}

// ---------------------------------------------------------------------------
extern "C" void kernel_launch(void* const* d_in, const int* in_sizes, int n_in,
                              void* d_out, int out_size, void* d_ws, size_t ws_size,
                              hipStream_t stream)
{
    const float* x  = (const float*)d_in[0];
    // d_in[1] = mask (bool tril): applied analytically — unused
    const float* Wq = (const float*)d_in[2];
    const float* bq = (const float*)d_in[3];
    const float* Wk = (const float*)d_in[4];
    const float* bk = (const float*)d_in[5];
    const float* Wv = (const float*)d_in[6];
    const float* bv = (const float*)d_in[7];
    const float* Wo = (const float*)d_in[8];
    const float* bo = (const float*)d_in[9];
    float* out = (float*)d_out;
    (void)d_ws; (void)ws_size;

    dim3 blk(256, 1, 1);
    hipLaunchKernelGGL(prep_kernel, dim3(4608), blk, 0, stream, x, Wq, Wk, Wv, Wo);
    hipLaunchKernelGGL(gemm128_kernel, dim3(24, 16), blk, 0, stream,
                       bq, bk, bv, (float*)nullptr, 0);
    hipLaunchKernelGGL(attn_kernel, dim3(16, 16, 2), blk, 0, stream);
    hipLaunchKernelGGL(gemm128_kernel, dim3(16, 16), blk, 0, stream,
                       bo, nullptr, nullptr, out, 1);
}

// Round 8
// 316.363 us; speedup vs baseline: 1.3199x; 1.0215x over previous
//
#include <hip/hip_runtime.h>

typedef __attribute__((ext_vector_type(8))) __bf16 bf16x8;
typedef __attribute__((ext_vector_type(8))) unsigned short u16x8;
typedef __attribute__((ext_vector_type(4))) float f32x4;

// Static device scratch (bf16):
//  xbf [2048][2048], WtQKV [3072][2048], WtO [2048][2048],
//  q [2048][2048], k [2048][512], vt [2][4][128][1024], att [2048][2048]
#define XBOFF 0
#define WQKVOFF (XBOFF + 2048 * 2048)
#define WOOFF   (WQKVOFF + 3072 * 2048)
#define QOFF    (WOOFF + 2048 * 2048)
#define KOFF    (QOFF + 2048 * 2048)
#define VTOFF   (KOFF + 2048 * 512)     // V pre-transposed: [b][g][d=128][s=1024]
#define AOFF    (VTOFF + 2048 * 512)
__device__ ushort g_scratch[AOFF + 2048 * 2048];

// nested (matryoshka) index -> full-layout index, H heads/groups, 128/head
__device__ __forceinline__ int nest_map(int n, int H) {
    int h = n >> 7, j = n & 127;
    if (j < 32) return h * 32 + j;
    if (j < 64) return H * 32 + h * 32 + (j - 32);
    return H * 64 + h * 64 + (j - 64);
}

__device__ __forceinline__ ushort f2bf(float f) {
    unsigned u = __builtin_bit_cast(unsigned, f);
    u += 0x7fffu + ((u >> 16) & 1u);
    return (ushort)(u >> 16);
}
__device__ __forceinline__ bf16x8 ld_frag(const ushort* p) {
    return __builtin_bit_cast(bf16x8, *(const u16x8*)p);
}
// async 16B global->LDS (m97 pattern); LDS base must be wave-uniform
__device__ __forceinline__ void glds16(const ushort* g, ushort* s) {
    __builtin_amdgcn_global_load_lds(
        (const __attribute__((address_space(1))) void*)g,
        (__attribute__((address_space(3))) void*)s, 16, 0, 0);
}

// ---------------------------------------------------------------------------
// Fused prep: one dispatch does x cvt + all 4 weight transposes.
// blocks [0,2048): x fp32->bf16.  [2048,3072): Wq^T  [3072,3328): Wk^T
// [3328,3584): Wv^T  [3584,4608): Wo^T (row-mapped)
// ---------------------------------------------------------------------------
__global__ __launch_bounds__(256) void prep_kernel(
    const float* __restrict__ x,
    const float* __restrict__ Wq, const float* __restrict__ Wk,
    const float* __restrict__ Wv, const float* __restrict__ Wo)
{
    const int bx = blockIdx.x;
    const int tid = threadIdx.x;

    if (bx < 2048) {   // ---- x convert ----
        size_t i = ((size_t)bx * 256 + tid) * 8;
        float4 f0 = *(const float4*)&x[i];
        float4 f1 = *(const float4*)&x[i + 4];
        union { uint4 v; ushort u[8]; } a;
        a.u[0] = f2bf(f0.x); a.u[1] = f2bf(f0.y); a.u[2] = f2bf(f0.z); a.u[3] = f2bf(f0.w);
        a.u[4] = f2bf(f1.x); a.u[5] = f2bf(f1.y); a.u[6] = f2bf(f1.z); a.u[7] = f2bf(f1.w);
        *(uint4*)&g_scratch[XBOFF + i] = a.v;
        return;
    }

    const float* W; int rowlen, H, mode, dstoff, t;
    if (bx < 3072)      { W = Wq; rowlen = 2048; H = 16; mode = 0; dstoff = WQKVOFF;               t = bx - 2048; }
    else if (bx < 3328) { W = Wk; rowlen = 512;  H = 4;  mode = 0; dstoff = WQKVOFF + 2048 * 2048; t = bx - 3072; }
    else if (bx < 3584) { W = Wv; rowlen = 512;  H = 4;  mode = 0; dstoff = WQKVOFF + 2560 * 2048; t = bx - 3328; }
    else                { W = Wo; rowlen = 2048; H = 16; mode = 1; dstoff = WOOFF;                 t = bx - 3584; }
    const int k0 = (t & 31) * 64;
    const int n0 = (t >> 5) * 64;

    __shared__ ushort T[64][66];
    const int r = tid >> 3, oct = tid & 7;

    #pragma unroll
    for (int rep = 0; rep < 2; ++rep) {
        int rr = r + rep * 32;
        int wrow = mode ? nest_map(k0 + rr, 16) : (k0 + rr);
        int wcol = mode ? (n0 + oct * 8) : nest_map(n0 + oct * 8, H);
        float4 f0 = *(const float4*)&W[(size_t)wrow * rowlen + wcol];
        float4 f1 = *(const float4*)&W[(size_t)wrow * rowlen + wcol + 4];
        ushort* d = &T[rr][oct * 8];
        d[0] = f2bf(f0.x); d[1] = f2bf(f0.y); d[2] = f2bf(f0.z); d[3] = f2bf(f0.w);
        d[4] = f2bf(f1.x); d[5] = f2bf(f1.y); d[6] = f2bf(f1.z); d[7] = f2bf(f1.w);
    }
    __syncthreads();
    #pragma unroll
    for (int rep = 0; rep < 2; ++rep) {
        int rr = r + rep * 32;
        union { uint4 v; ushort u[8]; } cv;
        #pragma unroll
        for (int i = 0; i < 8; ++i) cv.u[i] = T[oct * 8 + i][rr];
        *(uint4*)&g_scratch[dstoff + (size_t)(n0 + rr) * 2048 + k0 + oct * 8] = cv.v;
    }
}

// ---------------------------------------------------------------------------
// 128x128-tile GEMM, BK=64, global_load_lds(16B) staging into XOR-swizzled
// unpadded LDS. mode 0: A=xbf, Bt=WtQKV (N=3072) -> q | k natural | V^T global.
// mode 1: A=att, Bt=WtO -> fp32 out. V-blocks (n0>=2560) transpose their
// 128x128 output tile through the (now free) staging LDS and write vt[g][d][s].
// ---------------------------------------------------------------------------
__global__ __launch_bounds__(256) void gemm128_kernel(
    const float* __restrict__ b0, const float* __restrict__ b1,
    const float* __restrict__ b2, float* __restrict__ oext, int mode)
{
    __shared__ __align__(16) ushort SH[2 * 128 * 64];
    ushort* As = SH;
    ushort* Bs = SH + 128 * 64;
    const int n0 = blockIdx.x * 128;
    const int m0 = blockIdx.y * 128;
    const int tid = threadIdx.x;
    const int lane = tid & 63, wid = tid >> 6;
    const int wm = wid & 1, wn = wid >> 1;
    const int quad = lane >> 4, l16 = lane & 15;

    const ushort* A  = g_scratch + (mode ? AOFF : XBOFF);
    const ushort* Bt = g_scratch + (mode ? WOOFF : WQKVOFF);

    const bool vpath = (mode == 0) && (n0 >= 2560);
    const float* bias; ushort* outS = nullptr; int c0, oldim, H;
    if (mode == 1)      { bias = b0; c0 = n0; oldim = 2048; H = 0; }
    else if (n0 < 2048) { bias = b0; outS = g_scratch + QOFF; c0 = n0;        oldim = 2048; H = 16; }
    else if (n0 < 2560) { bias = b1; outS = g_scratch + KOFF; c0 = n0 - 2048; oldim = 512;  H = 4; }
    else                { bias = b2; outS = nullptr;          c0 = n0 - 2560; oldim = 512;  H = 4; }

    const int lrow = lane >> 3;
    const int lchunk = (lane & 7) ^ (lrow & 7);

    f32x4 acc[4][4];
    #pragma unroll
    for (int a = 0; a < 4; ++a)
        #pragma unroll
        for (int c = 0; c < 4; ++c) acc[a][c] = f32x4{0.f, 0.f, 0.f, 0.f};

    for (int kt = 0; kt < 32; ++kt) {
        const int k0 = kt * 64;
        #pragma unroll
        for (int it = 0; it < 4; ++it) {
            int rb = it * 32 + wid * 8;            // wave-uniform row base
            int r  = rb + lrow;
            glds16(&A[(size_t)(m0 + r) * 2048 + k0 + lchunk * 8], &As[rb * 64]);
            glds16(&Bt[(size_t)(n0 + r) * 2048 + k0 + lchunk * 8], &Bs[rb * 64]);
        }
        __syncthreads();
        #pragma unroll
        for (int kc = 0; kc < 2; ++kc) {
            bf16x8 af[4], bf[4];
            #pragma unroll
            for (int s = 0; s < 4; ++s) {
                int ra = wm * 64 + s * 16 + l16;
                int rbv = wn * 64 + s * 16 + l16;
                int ch = kc * 4 + quad;
                af[s] = ld_frag(&As[ra * 64 + ((ch ^ (ra & 7)) * 8)]);
                bf[s] = ld_frag(&Bs[rbv * 64 + ((ch ^ (rbv & 7)) * 8)]);
            }
            #pragma unroll
            for (int sm = 0; sm < 4; ++sm)
                #pragma unroll
                for (int sn = 0; sn < 4; ++sn)
                    acc[sm][sn] = __builtin_amdgcn_mfma_f32_16x16x32_bf16(
                        af[sm], bf[sn], acc[sm][sn], 0, 0, 0);
        }
        __syncthreads();
    }

    if (vpath) {
        // transpose 128x128 tile through SH (xor-swizzled), write vt[b][g][d][s]
        #pragma unroll
        for (int sm = 0; sm < 4; ++sm)
        #pragma unroll
        for (int sn = 0; sn < 4; ++sn)
        #pragma unroll
        for (int i = 0; i < 4; ++i) {
            int r = wm * 64 + sm * 16 + quad * 4 + i;       // spos-local
            int loc = wn * 64 + sn * 16 + l16;              // d-local (=g*128+d global col)
            float v = acc[sm][sn][i] + bias[nest_map(c0 + loc, 4)];
            SH[loc * 128 + (r ^ ((loc & 7) << 3))] = f2bf(v);
        }
        __syncthreads();
        const int dloc = tid >> 1, half = tid & 1;
        const int gg = c0 >> 7, bb = m0 >> 10, sb = m0 & 1023;
        ushort* vt = g_scratch + VTOFF;
        #pragma unroll
        for (int j = 0; j < 8; ++j) {
            int r = half * 64 + j * 8;
            uint4 v = *(uint4*)&SH[dloc * 128 + (r ^ ((dloc & 7) << 3))];
            *(uint4*)&vt[((size_t)((bb * 4 + gg) * 128 + dloc)) * 1024 + sb + r] = v;
        }
    } else {
        #pragma unroll
        for (int sm = 0; sm < 4; ++sm)
        #pragma unroll
        for (int sn = 0; sn < 4; ++sn)
        #pragma unroll
        for (int i = 0; i < 4; ++i) {
            int row = m0 + wm * 64 + sm * 16 + quad * 4 + i;
            int loc = wn * 64 + sn * 16 + l16;
            float v = acc[sm][sn][i];
            if (mode == 1) {
                oext[(size_t)row * 2048 + c0 + loc] = v + bias[c0 + loc];
            } else {
                v += bias[nest_map(c0 + loc, H)];
                outS[(size_t)row * oldim + c0 + loc] = f2bf(v);
            }
        }
    }
}

// ---------------------------------------------------------------------------
// Matryoshka flash attention. Grid (16,16,2), 4 waves; wave w owns q-rows
// [w*16,w*16+16). qt = 15 - blockIdx.x. QK computed once with cumulative
// per-level snapshot accumulators; 3 softmax chains interleaved (ILP);
// V staged from pre-transposed global vt via b128 (no scatter).
// ---------------------------------------------------------------------------
__global__ __launch_bounds__(256) void attn_kernel()
{
    const ushort* qb = g_scratch + QOFF;   // [B,S,16,128] nested
    const ushort* kb = g_scratch + KOFF;   // [B,S,4,128]
    const ushort* vt = g_scratch + VTOFF;  // [B,4,128,1024]
    ushort* att = g_scratch + AOFF;        // [B,S,16,128] nested

    __shared__ ushort Ks[64][136];
    __shared__ ushort Vt[128][72];   // rows=d, cols=kpos (b128 staged)
    __shared__ ushort Ps[64][72];    // P round-trip (wave-private rows)

    const int qt = 15 - blockIdx.x, h = blockIdx.y, b = blockIdx.z;
    const int g = h >> 2;
    const int q0 = qt * 64;
    const int tid = threadIdx.x;
    const int lane = tid & 63, w = tid >> 6;
    const int quad = lane >> 4, l16 = lane & 15;

    bf16x8 qa[4];
    {
        const ushort* qrow =
            qb + ((size_t)((b * 1024 + q0 + w * 16 + l16) * 16 + h)) * 128;
        #pragma unroll
        for (int kc = 0; kc < 4; ++kc)
            qa[kc] = ld_frag(qrow + kc * 32 + quad * 8);
    }

    float m_s[3][4], l_s[3][4];
    #pragma unroll
    for (int l = 0; l < 3; ++l)
        #pragma unroll
        for (int i = 0; i < 4; ++i) { m_s[l][i] = -1e9f; l_s[l][i] = 0.0f; }
    f32x4 oacc[8];
    #pragma unroll
    for (int t2 = 0; t2 < 8; ++t2) oacc[t2] = f32x4{0.f, 0.f, 0.f, 0.f};
    const f32x4 fz = {0.f, 0.f, 0.f, 0.f};

    for (int kt = 0; kt <= qt; ++kt) {
        const int k0 = kt * 64;
        {   // stage K natural (b128) + Vt from global vt (b128, no scatter)
            int r16 = tid >> 4, oct16 = tid & 15;
            #pragma unroll
            for (int rep = 0; rep < 4; ++rep) {
                int row = r16 + rep * 16;
                *(uint4*)&Ks[row][oct16 * 8] =
                    *(const uint4*)&kb[(size_t)((b * 1024 + k0 + row) * 4 + g) * 128 + oct16 * 8];
            }
            int oct = tid & 7, dr = tid >> 3;
            #pragma unroll
            for (int rep = 0; rep < 4; ++rep) {
                int d = dr + rep * 32;
                *(uint4*)&Vt[d][oct * 8] =
                    *(const uint4*)&vt[((size_t)((b * 4 + g) * 128 + d)) * 1024 + k0 + oct * 8];
            }
        }
        __syncthreads();

        const bool diag = (kt == qt);

        // QK^T, cumulative snapshots: s0 (dims 0:32), s1 (0:64), s2 (0:128)
        f32x4 s0[4], s1[4], s2[4];
        #pragma unroll
        for (int n = 0; n < 4; ++n)
            s0[n] = __builtin_amdgcn_mfma_f32_16x16x32_bf16(
                qa[0], ld_frag(&Ks[n * 16 + l16][quad * 8]), fz, 0, 0, 0);
        #pragma unroll
        for (int n = 0; n < 4; ++n)
            s1[n] = __builtin_amdgcn_mfma_f32_16x16x32_bf16(
                qa[1], ld_frag(&Ks[n * 16 + l16][32 + quad * 8]), s0[n], 0, 0, 0);
        #pragma unroll
        for (int n = 0; n < 4; ++n)
            s2[n] = __builtin_amdgcn_mfma_f32_16x16x32_bf16(
                qa[2], ld_frag(&Ks[n * 16 + l16][64 + quad * 8]), s1[n], 0, 0, 0);
        #pragma unroll
        for (int n = 0; n < 4; ++n)
            s2[n] = __builtin_amdgcn_mfma_f32_16x16x32_bf16(
                qa[3], ld_frag(&Ks[n * 16 + l16][96 + quad * 8]), s2[n], 0, 0, 0);

        // interleaved 3-level online softmax (independent chains -> ILP)
        float sv[3][4][4], mx[3][4];
        #pragma unroll
        for (int l = 0; l < 3; ++l)
            #pragma unroll
            for (int i = 0; i < 4; ++i) mx[l][i] = -1e9f;
        #pragma unroll
        for (int n = 0; n < 4; ++n)
            #pragma unroll
            for (int i = 0; i < 4; ++i) {
                bool msk = diag &&
                    (k0 + n * 16 + l16 > q0 + w * 16 + quad * 4 + i);
                float x0 = msk ? -1e9f : s0[n][i] * 0.1767766953f;
                float x1 = msk ? -1e9f : s1[n][i] * 0.125f;
                float x2 = msk ? -1e9f : s2[n][i] * 0.0883883476f;
                sv[0][n][i] = x0; mx[0][i] = fmaxf(mx[0][i], x0);
                sv[1][n][i] = x1; mx[1][i] = fmaxf(mx[1][i], x1);
                sv[2][n][i] = x2; mx[2][i] = fmaxf(mx[2][i], x2);
            }
        #pragma unroll
        for (int d = 1; d < 16; d <<= 1)
            #pragma unroll
            for (int l = 0; l < 3; ++l)
                #pragma unroll
                for (int i = 0; i < 4; ++i)
                    mx[l][i] = fmaxf(mx[l][i], __shfl_xor(mx[l][i], d, 64));
        float al[3][4], rs[3][4];
        #pragma unroll
        for (int l = 0; l < 3; ++l)
            #pragma unroll
            for (int i = 0; i < 4; ++i) {
                float mn = fmaxf(m_s[l][i], mx[l][i]);
                al[l][i] = __expf(m_s[l][i] - mn);
                m_s[l][i] = mn;
                rs[l][i] = 0.f;
            }
        #pragma unroll
        for (int n = 0; n < 4; ++n)
            #pragma unroll
            for (int l = 0; l < 3; ++l)
                #pragma unroll
                for (int i = 0; i < 4; ++i) {
                    float p = __expf(sv[l][n][i] - m_s[l][i]);
                    sv[l][n][i] = p;
                    rs[l][i] += p;
                }
        #pragma unroll
        for (int d = 1; d < 16; d <<= 1)
            #pragma unroll
            for (int l = 0; l < 3; ++l)
                #pragma unroll
                for (int i = 0; i < 4; ++i)
                    rs[l][i] += __shfl_xor(rs[l][i], d, 64);
        #pragma unroll
        for (int l = 0; l < 3; ++l)
            #pragma unroll
            for (int i = 0; i < 4; ++i)
                l_s[l][i] = l_s[l][i] * al[l][i] + rs[l][i];
        #pragma unroll
        for (int t = 0; t < 8; ++t) {
            int lvl = (t < 2) ? 0 : (t < 4) ? 1 : 2;
            #pragma unroll
            for (int i = 0; i < 4; ++i) oacc[t][i] *= al[lvl][i];
        }

        // per-level Ps roundtrip + PV (same-wave in-order LDS => no barriers)
        const int obase[3] = {0, 2, 4}, onts[3] = {2, 2, 4}, voffs[3] = {0, 32, 64};
        #pragma unroll
        for (int l = 0; l < 3; ++l) {
            #pragma unroll
            for (int n = 0; n < 4; ++n)
                #pragma unroll
                for (int i = 0; i < 4; ++i)
                    Ps[w * 16 + quad * 4 + i][n * 16 + l16] = f2bf(sv[l][n][i]);
            #pragma unroll
            for (int kc = 0; kc < 2; ++kc) {
                bf16x8 pa = ld_frag(&Ps[w * 16 + l16][kc * 32 + quad * 8]);
                #pragma unroll
                for (int t = 0; t < 4; ++t) {
                    if (t < onts[l]) {
                        int vd = voffs[l] + t * 16 + l16;
                        bf16x8 vf = ld_frag(&Vt[vd][kc * 32 + quad * 8]);
                        oacc[obase[l] + t] = __builtin_amdgcn_mfma_f32_16x16x32_bf16(
                            pa, vf, oacc[obase[l] + t], 0, 0, 0);
                    }
                }
            }
        }
        __syncthreads();   // WAR: Ks/Vt reads done before next staging
    }

    float inv[3][4];
    #pragma unroll
    for (int l = 0; l < 3; ++l)
        #pragma unroll
        for (int i = 0; i < 4; ++i) {
            float L = l_s[l][i];
            inv[l][i] = (L > 0.f) ? (1.0f / L) : 0.f;
        }
    #pragma unroll
    for (int t = 0; t < 8; ++t) {
        int lvl = (t < 2) ? 0 : (t < 4) ? 1 : 2;
        #pragma unroll
        for (int i = 0; i < 4; ++i) {
            int srow = q0 + w * 16 + quad * 4 + i;
            att[(size_t)((b * 1024 + srow) * 16 + h) * 128 + t * 16 + l16] =
                f2bf(oacc[t][i] * inv[lvl][i]);
        }
    }
}

// ---------------------------------------------------------------------------
extern "C" void kernel_launch(void* const* d_in, const int* in_sizes, int n_in,
                              void* d_out, int out_size, void* d_ws, size_t ws_size,
                              hipStream_t stream)
{
    const float* x  = (const float*)d_in[0];
    // d_in[1] = mask (bool tril): applied analytically — unused
    const float* Wq = (const float*)d_in[2];
    const float* bq = (const float*)d_in[3];
    const float* Wk = (const float*)d_in[4];
    const float* bk = (const float*)d_in[5];
    const float* Wv = (const float*)d_in[6];
    const float* bv = (const float*)d_in[7];
    const float* Wo = (const float*)d_in[8];
    const float* bo = (const float*)d_in[9];
    float* out = (float*)d_out;
    (void)d_ws; (void)ws_size;

    dim3 blk(256, 1, 1);
    hipLaunchKernelGGL(prep_kernel, dim3(4608), blk, 0, stream, x, Wq, Wk, Wv, Wo);
    hipLaunchKernelGGL(gemm128_kernel, dim3(24, 16), blk, 0, stream,
                       bq, bk, bv, (float*)nullptr, 0);
    hipLaunchKernelGGL(attn_kernel, dim3(16, 16, 2), blk, 0, stream);
    hipLaunchKernelGGL(gemm128_kernel, dim3(16, 16), blk, 0, stream,
                       bo, nullptr, nullptr, out, 1);
}